// Round 2
// baseline (255.993 us; speedup 1.0000x reference)
//
#include <hip/hip_runtime.h>

// Causal self-attention fwd: x(4,2048,1024)fp32, W_qkv(1024,3072), W_proj(1024,1024)
// Pipeline: [transpose W->bf16] [x->bf16] [GEMM1 qkv + fused V-transpose] [RoPE q,k]
//           [flash attn] [GEMM2 out]
// R5: attn 32q/wave, paired Q-tiles, exp2 shift-free softmax.
// R6: swapped QK^T + in-register P via cvt_pk_bf16 + permlane swaps (no P LDS).
// R7: GEMM1 -> 256x256 8-phase counted-vmcnt template (T2/T3/T4/T5):
//     8 waves (2Mx4N), BK=64, LDS [2dbuf][A,B][2half][128x64] = 128KB, raw
//     s_barrier + vmcnt(4) at phases 1/4/5/8 (never 0 in loop), setprio around
//     MFMA clusters. GEMM2 (N=1024, only 128 tiles @256^2) stays on 128^2 kernel.

#define BATCH 4
#define SEQ   2048
#define DM    1024
#define NH    16
#define HD    64
#define QKV_W 3072

typedef short bf16x8 __attribute__((ext_vector_type(8)));
typedef float f32x4  __attribute__((ext_vector_type(4)));
typedef unsigned u32x4 __attribute__((ext_vector_type(4)));
typedef unsigned short bf16_t;

__device__ __forceinline__ unsigned short f2bf(float f) {
  unsigned u = __float_as_uint(f);
  u += 0x7fffu + ((u >> 16) & 1u);   // round-to-nearest-even
  return (unsigned short)(u >> 16);
}
__device__ __forceinline__ float bf2f(unsigned short s) {
  return __uint_as_float((unsigned)s << 16);
}
// async global->LDS, 16B per lane; LDS dest is wave-uniform base + lane*16
__device__ __forceinline__ void gld16(const void* g, void* l) {
  __builtin_amdgcn_global_load_lds(
      (const __attribute__((address_space(1))) unsigned int*)g,
      (__attribute__((address_space(3))) unsigned int*)l, 16, 0, 0);
}
// packed f32x2 -> bf16x2 (RTNE), lo=a hi=b
__device__ __forceinline__ unsigned cvt_pk_bf16(float a, float b) {
  unsigned r;
  asm("v_cvt_pk_bf16_f32 %0, %1, %2" : "=v"(r) : "v"(a), "v"(b));
  return r;
}
// a.rows{2,3} <-> b.rows{0,1}  (rows = 16-lane groups)
__device__ __forceinline__ void permlane32_swap(unsigned& a, unsigned& b) {
  asm("v_permlane32_swap_b32 %0, %1" : "+v"(a), "+v"(b));
}
// a.rows{1,3} <-> b.rows{0,2}
__device__ __forceinline__ void permlane16_swap(unsigned& a, unsigned& b) {
  asm("v_permlane16_swap_b32 %0, %1" : "+v"(a), "+v"(b));
}

// ---------------- W[K][N] fp32 -> Wt[N][K] bf16 ----------------
__global__ __launch_bounds__(256) void k_transpose(const float* __restrict__ W,
                                                   bf16_t* __restrict__ Wt,
                                                   int K, int N) {
  __shared__ float tile[32][33];
  const int tx = threadIdx.x, ty = threadIdx.y;   // (32,8)
  const int n0 = blockIdx.x * 32, k0 = blockIdx.y * 32;
#pragma unroll
  for (int j = 0; j < 4; ++j)
    tile[ty + j * 8][tx] = W[(size_t)(k0 + ty + j * 8) * N + n0 + tx];
  __syncthreads();
#pragma unroll
  for (int j = 0; j < 4; ++j)
    Wt[(size_t)(n0 + ty + j * 8) * K + k0 + tx] = f2bf(tile[tx][ty + j * 8]);
}

// ---------------- fp32 -> bf16 elementwise ----------------
__global__ __launch_bounds__(256) void k_cvt(const float* __restrict__ x,
                                             bf16_t* __restrict__ xb) {
  const int i = (blockIdx.x * 256 + threadIdx.x) * 4;
  float4 v = *(const float4*)(x + i);
  unsigned lo = (unsigned)f2bf(v.x) | ((unsigned)f2bf(v.y) << 16);
  unsigned hi = (unsigned)f2bf(v.z) | ((unsigned)f2bf(v.w) << 16);
  *(uint2*)(xb + i) = make_uint2(lo, hi);
}

// ---------------- RoPE in place on q,k sections of qkv ----------------
__global__ __launch_bounds__(256) void k_rope(bf16_t* __restrict__ qkv) {
  const int t = blockIdx.x * 256 + threadIdx.x;
  const int i = t & 31;            // freq index 0..31
  const int h = (t >> 5) & 15;     // head
  const int s = (t >> 9) & 2047;   // position
  const int b = t >> 20;
  const float inv = __expf((float)i * -0.28782313662425575f); // -ln(10000)/32
  float sn, cs;
  sincosf((float)s * inv, &sn, &cs);
  size_t base = ((size_t)(b * SEQ + s)) * QKV_W + h * HD + 2 * i;
#pragma unroll
  for (int part = 0; part < 2; ++part) {      // q then k
    unsigned u = *(unsigned*)(qkv + base + part * DM);
    float e = bf2f((unsigned short)(u & 0xffffu));
    float o = bf2f((unsigned short)(u >> 16));
    unsigned short e2 = f2bf(e * cs - o * sn);
    unsigned short o2 = f2bf(e * sn + o * cs);
    *(unsigned*)(qkv + base + part * DM) = (unsigned)e2 | ((unsigned)o2 << 16);
  }
}

// ---------------- 128x128 bf16 GEMM (2-phase) — used for GEMM2 ----------------
template<int MODE>
__global__ __launch_bounds__(256) void k_gemm(const bf16_t* __restrict__ A,
                                              const bf16_t* __restrict__ Bt,
                                              void* __restrict__ Cout,
                                              bf16_t* __restrict__ vt,
                                              int M, int N, int K) {
  __shared__ __align__(16) short As[128 * 64];
  __shared__ __align__(16) short Bs[128 * 64];
  const int tid = threadIdx.x;
  const int wave = tid >> 6, lane = tid & 63;
  const int quad = lane >> 4, l16 = lane & 15;
  const int wm = (wave >> 1) * 64, wn = (wave & 1) * 64;
  const int bm = blockIdx.y * 128, bn = blockIdx.x * 128;

  f32x4 acc[4][4];
#pragma unroll
  for (int i = 0; i < 4; ++i)
#pragma unroll
    for (int j = 0; j < 4; ++j) acc[i][j] = f32x4{0.f, 0.f, 0.f, 0.f};

  const int srow = tid >> 3;                       // 0..31
  const int sg   = (tid & 7) ^ (srow & 7);         // swizzled source granule
  const bf16_t* Ap = A  + (size_t)(bm + srow) * K + sg * 8;
  const bf16_t* Bp = Bt + (size_t)(bn + srow) * K + sg * 8;
  short* Ad = As + tid * 8;
  short* Bd = Bs + tid * 8;

  for (int k0 = 0; k0 < K; k0 += 64) {
    __syncthreads();
#pragma unroll
    for (int pp = 0; pp < 4; ++pp) {
      gld16(Ap + (size_t)(pp * 32) * K + k0, Ad + pp * 2048);
      gld16(Bp + (size_t)(pp * 32) * K + k0, Bd + pp * 2048);
    }
    __syncthreads();
#pragma unroll
    for (int ks = 0; ks < 2; ++ks) {
      bf16x8 af[4], bfr[4];
#pragma unroll
      for (int i = 0; i < 4; ++i)
        af[i] = *(const bf16x8*)&As[(wm + i * 16 + l16) * 64 +
                                    (((ks * 4 + quad) ^ (l16 & 7)) << 3)];
#pragma unroll
      for (int j = 0; j < 4; ++j)
        bfr[j] = *(const bf16x8*)&Bs[(wn + j * 16 + l16) * 64 +
                                     (((ks * 4 + quad) ^ (l16 & 7)) << 3)];
#pragma unroll
      for (int i = 0; i < 4; ++i)
#pragma unroll
        for (int j = 0; j < 4; ++j)
          acc[i][j] = __builtin_amdgcn_mfma_f32_16x16x32_bf16(af[i], bfr[j], acc[i][j], 0, 0, 0);
    }
  }
#pragma unroll
  for (int i = 0; i < 4; ++i)
#pragma unroll
    for (int j = 0; j < 4; ++j) {
      const int col = bn + wn + j * 16 + l16;
      const int row0 = bm + wm + i * 16 + quad * 4;
      if (MODE == 1 && col >= 2048) {
        const int d = col - 2048;
        const int hh = d >> 6, dd = d & 63;
        const int bb = row0 >> 11, ss = row0 & 2047;
        ushort4 pk;
        pk.x = f2bf(acc[i][j][0]); pk.y = f2bf(acc[i][j][1]);
        pk.z = f2bf(acc[i][j][2]); pk.w = f2bf(acc[i][j][3]);
        *(ushort4*)(vt + ((size_t)((bb * NH + hh) * HD + dd)) * SEQ + ss) = pk;
      } else {
#pragma unroll
        for (int r = 0; r < 4; ++r) {
          if (MODE == 1)
            ((bf16_t*)Cout)[(size_t)(row0 + r) * N + col] = f2bf(acc[i][j][r]);
          else
            ((float*)Cout)[(size_t)(row0 + r) * N + col] = acc[i][j][r];
        }
      }
    }
}

// ---------------- 256x256 8-phase GEMM (counted vmcnt) — GEMM1 ----------------
// 8 waves: wave>>2 = A-half (128 rows), (wave&3) = 64-col B slice; per-wave C
// 128x64 = acc[8][4]. Per K-tile: 4 phases = C-quadrants (m0-3,n0-1)(m0-3,n2-3)
// (m4-7,n2-3)(m4-7,n0-1); B n0-1 frags stay live P1->P4. Stage ledger (1
// half-tile = 2 gld16/thread per phase):
//   P1:A1(kt+1) P2:B0(kt+1) P3:B1(kt+1) P4:A0(kt+2) P5:A1(kt+2) P6:B0(kt+2)
//   P7:B1(kt+2) P8:A0(kt+3)    [kt = even tile of this iter]
// WAR: each stage lands >=1 lgkm-drained barrier after its region's last read.
// vmcnt(4) at P1/P4/P5/P8 drains exactly the 3 half-tiles the next reads need.
template<int MODE>
__global__ __launch_bounds__(512, 2) void k_gemm8(const bf16_t* __restrict__ A,
                                                  const bf16_t* __restrict__ Bt,
                                                  void* __restrict__ Cout,
                                                  bf16_t* __restrict__ vt,
                                                  int M, int N, int K) {
  __shared__ __align__(16) short L[2][2][2][8192];  // [dbuf][A,B][half][128*64]
  const int tid = threadIdx.x;
  const int wave = tid >> 6, lane = tid & 63;
  const int quad = lane >> 4, l16 = lane & 15;
  const int ah = wave >> 2;              // A half (fixed per wave)
  const int bhh = (wave & 3) >> 1;       // B half (fixed per wave)
  const int wnn = (wave & 1) * 64;       // col base inside B half

  const int nbx = N >> 8;
  int bid = (int)blockIdx.x;
  const int cpx = (int)gridDim.x >> 3;   // gridDim.x % 8 == 0
  bid = (bid & 7) * cpx + (bid >> 3);    // XCD-contiguous
  const int bm = (bid / nbx) * 256, bn = (bid % nbx) * 256;

  f32x4 acc[8][4];
#pragma unroll
  for (int i = 0; i < 8; ++i)
#pragma unroll
    for (int j = 0; j < 4; ++j) acc[i][j] = f32x4{0.f, 0.f, 0.f, 0.f};

  const int sr = tid >> 3;                    // staging row 0..63 (per issue)
  const int sgr = (tid & 7) ^ (sr & 7);       // swizzled source granule
  const bf16_t* aSrc = A  + (size_t)(bm + sr) * K + sgr * 8;
  const bf16_t* bSrc = Bt + (size_t)(bn + sr) * K + sgr * 8;

  bf16x8 ra[4][2], rb[4][2];

#define SWZ8(ks) ((((ks) * 4 + quad) ^ (l16 & 7)) << 3)
#define STG(buf, ab, hf, kt)                                                   \
  do {                                                                         \
    const bf16_t* s_ = (ab) ? bSrc : aSrc;                                     \
    gld16(s_ + (size_t)((hf) * 128) * K + (size_t)(kt) * 64,                   \
          &L[buf][ab][hf][tid * 8]);                                           \
    gld16(s_ + (size_t)((hf) * 128 + 64) * K + (size_t)(kt) * 64,              \
          &L[buf][ab][hf][4096 + tid * 8]);                                    \
  } while (0)
#define LDA8(buf, mg)                                                          \
  do {                                                                         \
    _Pragma("unroll") for (int mi = 0; mi < 4; ++mi) {                         \
      ra[mi][0] = *(const bf16x8*)&L[buf][0][ah]                               \
          [((mg) * 64 + mi * 16 + l16) * 64 + SWZ8(0)];                        \
      ra[mi][1] = *(const bf16x8*)&L[buf][0][ah]                               \
          [((mg) * 64 + mi * 16 + l16) * 64 + SWZ8(1)];                        \
    }                                                                          \
  } while (0)
#define LDB8(buf, np)                                                          \
  do {                                                                         \
    _Pragma("unroll") for (int nj = 0; nj < 2; ++nj) {                         \
      rb[(np) * 2 + nj][0] = *(const bf16x8*)&L[buf][1][bhh]                   \
          [(wnn + (np) * 32 + nj * 16 + l16) * 64 + SWZ8(0)];                  \
      rb[(np) * 2 + nj][1] = *(const bf16x8*)&L[buf][1][bhh]                   \
          [(wnn + (np) * 32 + nj * 16 + l16) * 64 + SWZ8(1)];                  \
    }                                                                          \
  } while (0)
#define MM8(mg, np)                                                            \
  do {                                                                         \
    __builtin_amdgcn_s_setprio(1);                                             \
    _Pragma("unroll") for (int mi = 0; mi < 4; ++mi)                           \
      _Pragma("unroll") for (int nj = 0; nj < 2; ++nj) {                       \
        f32x4 c_ = acc[(mg) * 4 + mi][(np) * 2 + nj];                          \
        c_ = __builtin_amdgcn_mfma_f32_16x16x32_bf16(ra[mi][0],                \
                 rb[(np) * 2 + nj][0], c_, 0, 0, 0);                           \
        c_ = __builtin_amdgcn_mfma_f32_16x16x32_bf16(ra[mi][1],                \
                 rb[(np) * 2 + nj][1], c_, 0, 0, 0);                           \
        acc[(mg) * 4 + mi][(np) * 2 + nj] = c_;                                \
      }                                                                        \
    __builtin_amdgcn_s_setprio(0);                                             \
  } while (0)
#define BAR1 __builtin_amdgcn_s_barrier()
#define BAR2                                                                   \
  do {                                                                         \
    asm volatile("s_waitcnt lgkmcnt(0)" ::: "memory");                         \
    __builtin_amdgcn_s_barrier();                                              \
  } while (0)
#define WAITV(n) asm volatile("s_waitcnt vmcnt(" n ")" ::: "memory")

  // prologue: kt0 {A0,A1,B0,B1} + kt1 {A0}; drain kt0 A0,A1,B0
  STG(0, 0, 0, 0); STG(0, 0, 1, 0); STG(0, 1, 0, 0); STG(0, 1, 1, 0);
  STG(1, 0, 0, 1);
  WAITV("4");
  BAR1;

#pragma unroll 1
  for (int u = 0; u < 7; ++u) {
    const int k1 = 2 * u + 1, k2 = 2 * u + 2, k3 = 2 * u + 3;
    // P1
    LDA8(0, 0); LDB8(0, 0); STG(1, 0, 1, k1); WAITV("4"); BAR1; MM8(0, 0); BAR2;
    // P2
    LDB8(0, 1); STG(1, 1, 0, k1); BAR1; MM8(0, 1); BAR2;
    // P3
    LDA8(0, 1); STG(1, 1, 1, k1); BAR1; MM8(1, 1); BAR2;
    // P4
    STG(0, 0, 0, k2); WAITV("4"); BAR1; MM8(1, 0); BAR2;
    // P5
    LDA8(1, 0); LDB8(1, 0); STG(0, 0, 1, k2); WAITV("4"); BAR1; MM8(0, 0); BAR2;
    // P6
    LDB8(1, 1); STG(0, 1, 0, k2); BAR1; MM8(0, 1); BAR2;
    // P7
    LDA8(1, 1); STG(0, 1, 1, k2); BAR1; MM8(1, 1); BAR2;
    // P8
    STG(1, 0, 0, k3); WAITV("4"); BAR1; MM8(1, 0); BAR2;
  }
  // tail: kt14 (dbuf0), kt15 (dbuf1); stages only for kt15's A1,B0,B1
  LDA8(0, 0); LDB8(0, 0); STG(1, 0, 1, 15); WAITV("4"); BAR1; MM8(0, 0); BAR2;
  LDB8(0, 1); STG(1, 1, 0, 15); BAR1; MM8(0, 1); BAR2;
  LDA8(0, 1); STG(1, 1, 1, 15); BAR1; MM8(1, 1); BAR2;
  WAITV("2"); BAR1; MM8(1, 0); BAR2;
  LDA8(1, 0); LDB8(1, 0); WAITV("0"); BAR1; MM8(0, 0); BAR2;
  LDB8(1, 1); BAR1; MM8(0, 1); BAR2;
  LDA8(1, 1); BAR1; MM8(1, 1); BAR2;
  MM8(1, 0);

  // epilogue: C row = quad*4+reg, col = l16
#pragma unroll
  for (int m = 0; m < 8; ++m)
#pragma unroll
    for (int n = 0; n < 4; ++n) {
      const int col = bn + (wave & 3) * 64 + n * 16 + l16;
      const int row0 = bm + ah * 128 + m * 16 + quad * 4;
      if (MODE == 1 && col >= 2048) {
        const int d = col - 2048;
        const int hh = d >> 6, dd = d & 63;
        const int bb = row0 >> 11, ss = row0 & 2047;
        ushort4 pk;
        pk.x = f2bf(acc[m][n][0]); pk.y = f2bf(acc[m][n][1]);
        pk.z = f2bf(acc[m][n][2]); pk.w = f2bf(acc[m][n][3]);
        *(ushort4*)(vt + ((size_t)((bb * NH + hh) * HD + dd)) * SEQ + ss) = pk;
      } else {
#pragma unroll
        for (int r = 0; r < 4; ++r) {
          if (MODE == 1)
            ((bf16_t*)Cout)[(size_t)(row0 + r) * N + col] = f2bf(acc[m][n][r]);
          else
            ((float*)Cout)[(size_t)(row0 + r) * N + col] = acc[m][n][r];
        }
      }
    }
#undef SWZ8
#undef STG
#undef LDA8
#undef LDB8
#undef MM8
#undef BAR1
#undef BAR2
#undef WAITV
}

// ---------------- flash attention ----------------
// 512 blocks, XCD-swizzled. Block: 128 Q-rows (4 waves x 32q), Q-tiles (p,15-p)
// => uniform 34 KV-iters. KV dbuf + cross-iter prefetch, 1 barrier/iter.
// Q pre-scaled by 0.125*log2e => p = exp2(s'), shift-free (cancels in norm).
// Swapped QK^T: S^T = mfma(K, Q) so each lane holds P[q=l16][k=jn*16+quad*4+r];
// PV A-frags built in-register via cvt_pk + permlane32/16 swaps — no P LDS.
#define QSCALE 0.18033688011112042f   // 0.125 * log2(e)
__global__ __launch_bounds__(256, 2) void k_attn(const bf16_t* __restrict__ qkv,
                                                 const bf16_t* __restrict__ vt,
                                                 bf16_t* __restrict__ y) {
  __shared__ __align__(16) short KV[2][4][64 * 32];  // [buf][K0,K1,V0,V1]
  const int tid = threadIdx.x;
  const int lane = tid & 63;
  const int quad = lane >> 4, l16 = lane & 15;
  const int wave = tid >> 6;
  const int l = blockIdx.x;
  const int p = (l >> 3) & 7;                    // pair index 0..7
  const int g = ((l >> 6) << 3) | (l & 7);       // (h,b) group, const per XCD slice
  const int h = g & 15, b = g >> 4;
  const size_t bbase = (size_t)b * SEQ * QKV_W;
  const int srow = tid >> 2;            // staging row 0..63
  const int sc8  = (tid & 3) * 8;       // staging col 0,8,16,24
  const bf16_t* kbase = qkv + bbase + (size_t)srow * QKV_W + DM + h * HD + sc8;
  const bf16_t* vbase = vt + ((size_t)(b * NH + h) * HD + srow) * SEQ + sc8;

#define ISSUE(kv0, buf)                                              \
  do {                                                               \
    gld16(kbase + (size_t)(kv0) * QKV_W,      &KV[buf][0][tid * 8]); \
    gld16(kbase + (size_t)(kv0) * QKV_W + 32, &KV[buf][1][tid * 8]); \
    gld16(vbase + (kv0),                      &KV[buf][2][tid * 8]); \
    gld16(vbase + (kv0) + 32,                 &KV[buf][3][tid * 8]); \
  } while (0)

  int bufp = 0;
  ISSUE(0, 0);
  for (int half = 0; half < 2; ++half) {
    const int qt = half ? (15 - p) : p;
    const int qb = qt * 128 + wave * 32;         // wave's first q row
    // load + pre-scale Q fragments: aq[mi][kk]  (B-operand; layout == A layout)
    bf16x8 aq[2][2];
#pragma unroll
    for (int mi = 0; mi < 2; ++mi)
#pragma unroll
      for (int kk = 0; kk < 2; ++kk) {
        const bf16_t* qp = qkv + bbase + (size_t)(qb + mi * 16 + l16) * QKV_W +
                           h * HD + kk * 32 + quad * 8;
        bf16x8 raw = *(const bf16x8*)qp;
        bf16x8 sc;
#pragma unroll
        for (int e = 0; e < 8; ++e)
          sc[e] = (short)f2bf(bf2f((unsigned short)raw[e]) * QSCALE);
        aq[mi][kk] = sc;
      }
    f32x4 o[2][4];
    float lsum[2];
#pragma unroll
    for (int mi = 0; mi < 2; ++mi) {
      lsum[mi] = 0.f;
#pragma unroll
      for (int jn = 0; jn < 4; ++jn) o[mi][jn] = f32x4{0.f, 0.f, 0.f, 0.f};
    }
    const int qr0 = qb + l16;                    // this lane's q row (mi=0)

    const int jmax = 2 * qt + 1;
    for (int j = 0; j <= jmax; ++j) {
      const int kv0 = j * 64;
      __syncthreads();   // drains this buf's loads; WAR-protects prefetch target
      if (j < jmax)          ISSUE(kv0 + 64, bufp ^ 1);
      else if (half == 0)    ISSUE(0, bufp ^ 1);
      if (kv0 <= qb + 31) {  // else: fully masked for this wave — skip
        const bool needmask = (kv0 + 63 > qb);
        const short* Kc0 = &KV[bufp][0][0];
        const short* Kc1 = &KV[bufp][1][0];
        const short* Vc0 = &KV[bufp][2][0];
        const short* Vc1 = &KV[bufp][3][0];

        // S^T frags: st[jn][mi]; row = kv (jn*16+quad*4+r), col = q (mi*16+l16)
        f32x4 st[4][2];
#pragma unroll
        for (int jn = 0; jn < 4; ++jn) {
          bf16x8 ak0 = *(const bf16x8*)&Kc0[(jn * 16 + l16) * 32 + quad * 8];
          bf16x8 ak1 = *(const bf16x8*)&Kc1[(jn * 16 + l16) * 32 + quad * 8];
#pragma unroll
          for (int mi = 0; mi < 2; ++mi) {
            f32x4 s4 = f32x4{0.f, 0.f, 0.f, 0.f};
            s4 = __builtin_amdgcn_mfma_f32_16x16x32_bf16(ak0, aq[mi][0], s4, 0, 0, 0);
            s4 = __builtin_amdgcn_mfma_f32_16x16x32_bf16(ak1, aq[mi][1], s4, 0, 0, 0);
            st[jn][mi] = s4;
          }
        }
        // p = exp2(s'); mask near diagonal; pack r-pairs to bf16x2
        unsigned pk[4][2][2];
#pragma unroll
        for (int jn = 0; jn < 4; ++jn)
#pragma unroll
          for (int mi = 0; mi < 2; ++mi) {
            const int kvb = kv0 + jn * 16 + quad * 4;
            const int qr = qr0 + mi * 16;
            float e[4];
#pragma unroll
            for (int r = 0; r < 4; ++r) {
              float v = __builtin_amdgcn_exp2f(st[jn][mi][r]);
              if (needmask) v = (kvb + r <= qr) ? v : 0.f;
              lsum[mi] += v;
              e[r] = v;
            }
            pk[jn][mi][0] = cvt_pk_bf16(e[0], e[1]);
            pk[jn][mi][1] = cvt_pk_bf16(e[2], e[3]);
          }
        // redistribute across quads -> PV A-frags ap[mi][ks]
        bf16x8 ap[2][2];
#pragma unroll
        for (int mi = 0; mi < 2; ++mi)
#pragma unroll
          for (int ks = 0; ks < 2; ++ks) {
            unsigned a0 = pk[2 * ks][mi][0], b0 = pk[2 * ks + 1][mi][0];
            permlane32_swap(a0, b0);
            permlane16_swap(a0, b0);
            unsigned a1 = pk[2 * ks][mi][1], b1 = pk[2 * ks + 1][mi][1];
            permlane32_swap(a1, b1);
            permlane16_swap(a1, b1);
            union { u32x4 u; bf16x8 s; } f;
            f.u = (u32x4){a0, a1, b0, b1};
            ap[mi][ks] = f.s;
          }
        // O += P V  (V frags shared across mi)
#pragma unroll
        for (int ks = 0; ks < 2; ++ks) {
          const short* Vc = ks ? Vc1 : Vc0;
#pragma unroll
          for (int jn = 0; jn < 4; ++jn) {
            bf16x8 bv = *(const bf16x8*)&Vc[(jn * 16 + l16) * 32 + quad * 8];
            o[0][jn] = __builtin_amdgcn_mfma_f32_16x16x32_bf16(ap[0][ks], bv, o[0][jn], 0, 0, 0);
            o[1][jn] = __builtin_amdgcn_mfma_f32_16x16x32_bf16(ap[1][ks], bv, o[1][jn], 0, 0, 0);
          }
        }
      }
      bufp ^= 1;
    }
    // normalize + write: lane holds full row-sum for q = l16 (+mi*16) after
    // quad-reduce; redistribute inv to output rows (quad*4+r) via shfl.
#pragma unroll
    for (int mi = 0; mi < 2; ++mi) {
      float s = lsum[mi];
      s += __shfl_xor(s, 16, 64);
      s += __shfl_xor(s, 32, 64);
      const float inv = 1.0f / s;
#pragma unroll
      for (int r = 0; r < 4; ++r) {
        const float invr = __shfl(inv, quad * 4 + r, 64);
        const int qr = qb + mi * 16 + quad * 4 + r;
        bf16_t* yp = y + ((size_t)b * SEQ + qr) * DM + h * HD;
#pragma unroll
        for (int jn = 0; jn < 4; ++jn)
          yp[jn * 16 + l16] = f2bf(o[mi][jn][r] * invr);
      }
    }
  }
#undef ISSUE
}

extern "C" void kernel_launch(void* const* d_in, const int* in_sizes, int n_in,
                              void* d_out, int out_size, void* d_ws, size_t ws_size,
                              hipStream_t stream) {
  const float* x     = (const float*)d_in[0];
  const float* Wqkv  = (const float*)d_in[1];
  const float* Wproj = (const float*)d_in[2];
  float* out = (float*)d_out;
  char* ws = (char*)d_ws;
  // ws layout (72 MiB):
  bf16_t* qkv = (bf16_t*)(ws);                 // 48 MiB (V third unused)
  bf16_t* Wt1 = (bf16_t*)(ws + 50331648);      // 6 MiB
  bf16_t* Wt2 = (bf16_t*)(ws + 56623104);      // 2 MiB
  bf16_t* xb  = (bf16_t*)(ws + 58720256);      // 16 MiB (dead after GEMM1)
  bf16_t* y   = xb;                            // attn output aliases xb
  // V^T parked in d_out's first 16 MiB; dead before GEMM2 overwrites d_out.
  bf16_t* vt  = (bf16_t*)d_out;

  k_transpose<<<dim3(QKV_W / 32, DM / 32), dim3(32, 8), 0, stream>>>(Wqkv, Wt1, DM, QKV_W);
  k_transpose<<<dim3(DM / 32, DM / 32), dim3(32, 8), 0, stream>>>(Wproj, Wt2, DM, DM);
  k_cvt<<<(BATCH * SEQ * DM) / (4 * 256), 256, 0, stream>>>(x, xb);
  k_gemm8<1><<<dim3((QKV_W / 256) * ((BATCH * SEQ) / 256)), 512, 0, stream>>>(
      xb, Wt1, qkv, vt, BATCH * SEQ, QKV_W, DM);
  k_rope<<<(BATCH * SEQ * NH * 32) / 256, 256, 0, stream>>>(qkv);
  k_attn<<<512, 256, 0, stream>>>(qkv, vt, y);
  k_gemm<0><<<dim3(DM / 128, (BATCH * SEQ) / 128), 256, 0, stream>>>(
      y, Wt2, out, nullptr, BATCH * SEQ, DM, DM);
}